// Round 7
// baseline (383.427 us; speedup 1.0000x reference)
//
#include <hip/hip_runtime.h>
#include <hip/hip_bf16.h>
#include <stdint.h>

#define B_ 8
#define N_ 2048
#define F_ 64
#define FH_ 64
#define H_ 4
#define C_ (H_*FH_)
#define LOG2E 1.44269504088896340736f

typedef short short8 __attribute__((ext_vector_type(8)));   // 8 bf16 raw bits (4 VGPRs)
typedef float f32x4 __attribute__((ext_vector_type(4)));

// float -> bf16 raw bits (RNE)
__device__ __forceinline__ short f2bf(float f) {
    __hip_bfloat16 h = __float2bfloat16(f);
    return __builtin_bit_cast(short, h);
}

// ---------------- K0: WT[h][o][f] = bf16(W[h][f][o]) ----------------
__global__ __launch_bounds__(256) void k0_wt(const float* __restrict__ W,
                                             __hip_bfloat16* __restrict__ WT) {
    int idx = blockIdx.x * 256 + threadIdx.x;   // 16384 elems total
    int h = idx >> 12, rem = idx & 4095, o = rem >> 6, f = rem & 63;
    WT[idx] = __float2bfloat16(W[(h * F_ + f) * FH_ + o]);
}

// ---------------- K1: featsT = (X@W)^T via MFMA; epilogue: ss + exp tables ----------------
// featsT[b][h][o][n]; ss = log2e*s_self; e1t = e^{s_neigh}; e2t = e^{0.2 s_neigh}
__global__ __launch_bounds__(256) void k1_feats(const float* __restrict__ X,
                                                const __hip_bfloat16* __restrict__ WT,
                                                const float* __restrict__ a_self,
                                                const float* __restrict__ a_neigh,
                                                __hip_bfloat16* __restrict__ featsT,
                                                float* __restrict__ ss,
                                                float* __restrict__ e1t,
                                                float* __restrict__ e2t) {
    __shared__ float a_lds[2][FH_];
    __shared__ __hip_bfloat16 c_lds[FH_ * 72];  // padded leading dim 72 vs 64
    const int nb = blockIdx.x, h = blockIdx.y, b = blockIdx.z;
    const int tid = threadIdx.x;
    if (tid < 64)       a_lds[0][tid] = a_self[h * FH_ + tid];
    else if (tid < 128) a_lds[1][tid - 64] = a_neigh[h * FH_ + tid - 64];
    __syncthreads();

    const int wave = tid >> 6, lane = tid & 63;
    const int m = lane & 15, q = lane >> 4;
    const int nl = wave * 16 + m;               // local column 0..63
    const int n = nb * 64 + nl;                 // B-frag column (node index)
    f32x4 acc[4] = {};
#pragma unroll
    for (int ks = 0; ks < 2; ++ks) {            // K = F = 64, two steps of 32
        const float* xp = X + ((size_t)(b * N_ + n)) * F_ + ks * 32 + q * 8;
        float4 x0 = *(const float4*)xp;
        float4 x1 = *(const float4*)(xp + 4);
        short8 bfrag;
        bfrag[0] = f2bf(x0.x); bfrag[1] = f2bf(x0.y);
        bfrag[2] = f2bf(x0.z); bfrag[3] = f2bf(x0.w);
        bfrag[4] = f2bf(x1.x); bfrag[5] = f2bf(x1.y);
        bfrag[6] = f2bf(x1.z); bfrag[7] = f2bf(x1.w);
#pragma unroll
        for (int ot = 0; ot < 4; ++ot) {        // 64 output features = 4 row tiles
            short8 afrag = *(const short8*)(WT + ((size_t)(h * FH_ + ot * 16 + m)) * F_ + ks * 32 + q * 8);
            acc[ot] = __builtin_amdgcn_mfma_f32_16x16x32_bf16(afrag, bfrag, acc[ot], 0, 0, 0);
        }
    }
    float ssv = 0.f, snv = 0.f;
#pragma unroll
    for (int ot = 0; ot < 4; ++ot) {
#pragma unroll
        for (int r = 0; r < 4; ++r) {
            int orow = ot * 16 + q * 4 + r;     // C: row=(lane>>4)*4+r, col=lane&15
            float v = acc[ot][r];
            c_lds[orow * 72 + nl] = __float2bfloat16(v);
            ssv += v * a_lds[0][orow];
            snv += v * a_lds[1][orow];
        }
    }
    // reduce over the 4 q-groups that share column n
    ssv += __shfl_xor(ssv, 16); ssv += __shfl_xor(ssv, 32);
    snv += __shfl_xor(snv, 16); snv += __shfl_xor(snv, 32);
    __syncthreads();
    {   // coalesced featsT store: thread t -> feature o = t>>2, 16-col chunk (t&3)
        int o = tid >> 2, c = (tid & 3) * 16;
        const __hip_bfloat16* src = c_lds + o * 72 + c;
        __hip_bfloat16* dst = featsT + ((size_t)(b * H_ + h) * FH_ + o) * N_ + nb * 64 + c;
        *(uint4*)dst       = *(const uint4*)src;        // 8 bf16
        *(uint4*)(dst + 8) = *(const uint4*)(src + 8);  // 8 bf16
    }
    if (lane < 16) {
        size_t idx = ((size_t)(b * H_ + h)) * N_ + n;
        float sl = snv * LOG2E;
        ss[idx]  = ssv * LOG2E;
        e1t[idx] = exp2f(sl);
        e2t[idx] = exp2f(0.2f * sl);
    }
}

// ---------------- K3: fused mask+softmax(no-max)+PV MFMA + epilogue ----------------
// grid (N/16, B); block = 4 waves = 4 heads, same 16 rows (A stream shared via L1).
// No LDS. exp(leaky(si+sj)) = (hi>1 ? hi : lo), hi = e1i*e1j, lo = e2i*e2j.
__global__ __launch_bounds__(256) void k3_attn(const float* __restrict__ A,
                                               const __hip_bfloat16* __restrict__ featsT,
                                               const float* __restrict__ ss,
                                               const float* __restrict__ e1t,
                                               const float* __restrict__ e2t,
                                               const float* __restrict__ bias,
                                               float* __restrict__ out) {
    const int tile = blockIdx.x, b = blockIdx.y;
    const int tid = threadIdx.x, h = tid >> 6, lane = tid & 63;
    const int m = lane & 15, q = lane >> 4;
    const int rowbase = tile * 16;

    const float ss0 = ss[((size_t)(b * H_ + h)) * N_ + rowbase + m];
    const float e1i = exp2f(ss0), e2i = exp2f(0.2f * ss0);

    const float* arow = A + ((size_t)(b * N_ + rowbase + m)) * N_ + q * 8;
    const __hip_bfloat16* fb = featsT + (((size_t)(b * H_ + h)) * FH_ + m) * N_ + q * 8;
    const float* p1 = e1t + ((size_t)(b * H_ + h)) * N_ + q * 8;
    const float* p2 = e2t + ((size_t)(b * H_ + h)) * N_ + q * 8;

    f32x4 acc[4] = {};
    f32x4 accl = {};
    short8 ones;
#pragma unroll
    for (int s = 0; s < 8; ++s) ones[s] = (short)0x3F80;   // bf16 1.0

    // --- depth-1 software prefetch of all four streams ---
    float4 cA0 = *(const float4*)(arow);
    float4 cA1 = *(const float4*)(arow + 4);
    short8 cF0 = *(const short8*)(fb);
    short8 cF1 = *(const short8*)(fb + (size_t)16 * N_);
    short8 cF2 = *(const short8*)(fb + (size_t)32 * N_);
    short8 cF3 = *(const short8*)(fb + (size_t)48 * N_);
    float4 cE10 = *(const float4*)(p1);
    float4 cE11 = *(const float4*)(p1 + 4);
    float4 cE20 = *(const float4*)(p2);
    float4 cE21 = *(const float4*)(p2 + 4);

#pragma unroll 2
    for (int jb = 0; jb < N_; jb += 32) {
        const int jn = (jb + 32) & (N_ - 1);    // wraps to 0 on last iter (unused)
        float4 nA0 = *(const float4*)(arow + jn);
        float4 nA1 = *(const float4*)(arow + jn + 4);
        short8 nF0 = *(const short8*)(fb + jn);
        short8 nF1 = *(const short8*)(fb + (size_t)16 * N_ + jn);
        short8 nF2 = *(const short8*)(fb + (size_t)32 * N_ + jn);
        short8 nF3 = *(const short8*)(fb + (size_t)48 * N_ + jn);
        float4 nE10 = *(const float4*)(p1 + jn);
        float4 nE11 = *(const float4*)(p1 + jn + 4);
        float4 nE20 = *(const float4*)(p2 + jn);
        float4 nE21 = *(const float4*)(p2 + jn + 4);

        float e1a[8] = {cE10.x, cE10.y, cE10.z, cE10.w, cE11.x, cE11.y, cE11.z, cE11.w};
        float e2a[8] = {cE20.x, cE20.y, cE20.z, cE20.w, cE21.x, cE21.y, cE21.z, cE21.w};
        float mk[8]  = {cA0.x, cA0.y, cA0.z, cA0.w, cA1.x, cA1.y, cA1.z, cA1.w};
        short8 p;
#pragma unroll
        for (int s = 0; s < 8; ++s) {
            float hi = e1i * e1a[s];
            float lo = e2i * e2a[s];
            float v = (hi > 1.0f) ? hi : lo;    // exp2(leaky(s)), sign test exact
            p[s] = f2bf(mk[s] * v);             // adjacency mask in {0,1}
        }
        acc[0] = __builtin_amdgcn_mfma_f32_16x16x32_bf16(p, cF0, acc[0], 0, 0, 0);
        acc[1] = __builtin_amdgcn_mfma_f32_16x16x32_bf16(p, cF1, acc[1], 0, 0, 0);
        acc[2] = __builtin_amdgcn_mfma_f32_16x16x32_bf16(p, cF2, acc[2], 0, 0, 0);
        acc[3] = __builtin_amdgcn_mfma_f32_16x16x32_bf16(p, cF3, acc[3], 0, 0, 0);
        accl   = __builtin_amdgcn_mfma_f32_16x16x32_bf16(p, ones, accl, 0, 0, 0);

        cA0 = nA0; cA1 = nA1;
        cF0 = nF0; cF1 = nF1; cF2 = nF2; cF3 = nF3;
        cE10 = nE10; cE11 = nE11; cE20 = nE20; cE21 = nE21;
    }

    float bc[4];
#pragma unroll
    for (int ct = 0; ct < 4; ++ct) bc[ct] = bias[h * FH_ + ct * 16 + m];

#pragma unroll
    for (int r = 0; r < 4; ++r) {
        float inv = 1.0f / accl[r];             // row sum (all cols identical)
        int gr = rowbase + q * 4 + r;
#pragma unroll
        for (int ct = 0; ct < 4; ++ct) {
            float v = acc[ct][r] * inv + bc[ct];
            out[((size_t)(b * N_) + gr) * C_ + h * FH_ + ct * 16 + m] = fmaxf(v, 0.0f);
        }
    }
}

extern "C" void kernel_launch(void* const* d_in, const int* in_sizes, int n_in,
                              void* d_out, int out_size, void* d_ws, size_t ws_size,
                              hipStream_t stream) {
    const float* X       = (const float*)d_in[0];
    const float* A       = (const float*)d_in[1];
    const float* W       = (const float*)d_in[2];
    const float* bias    = (const float*)d_in[3];
    const float* a_self  = (const float*)d_in[4];
    const float* a_neigh = (const float*)d_in[5];
    float* out = (float*)d_out;   // reference output dtype is float32

    char* ws = (char*)d_ws;
    __hip_bfloat16* featsT = (__hip_bfloat16*)(ws);             // 8 MB   [B][H][FH][N]
    __hip_bfloat16* WT     = (__hip_bfloat16*)(ws + 8388608);   // 32 KB  [H][FH][F]
    float* ss              = (float*)(ws + 8421376);            // 256 KB [B][H][N]
    float* e1t             = (float*)(ws + 8683520);            // 256 KB [B][H][N]
    float* e2t             = (float*)(ws + 8945664);            // 256 KB [B][H][N]

    k0_wt    <<<64, 256, 0, stream>>>(W, WT);
    k1_feats <<<dim3(N_ / 64, H_, B_), 256, 0, stream>>>(X, WT, a_self, a_neigh, featsT, ss, e1t, e2t);
    k3_attn  <<<dim3(N_ / 16, B_), 256, 0, stream>>>(A, featsT, ss, e1t, e2t, bias, out);
}

// Round 8
// 353.914 us; speedup vs baseline: 1.0834x; 1.0834x over previous
//
#include <hip/hip_runtime.h>
#include <hip/hip_bf16.h>
#include <stdint.h>

#define B_ 8
#define N_ 2048
#define F_ 64
#define FH_ 64
#define H_ 4
#define C_ (H_*FH_)
#define LOG2E 1.44269504088896340736f

typedef short short8 __attribute__((ext_vector_type(8)));   // 8 bf16 raw bits (4 VGPRs)
typedef float f32x4 __attribute__((ext_vector_type(4)));

// float -> bf16 raw bits (RNE)
__device__ __forceinline__ short f2bf(float f) {
    __hip_bfloat16 h = __float2bfloat16(f);
    return __builtin_bit_cast(short, h);
}

// ---------------- K0: WT[h][o][f] = bf16(W[h][f][o]) ----------------
__global__ __launch_bounds__(256) void k0_wt(const float* __restrict__ W,
                                             __hip_bfloat16* __restrict__ WT) {
    int idx = blockIdx.x * 256 + threadIdx.x;   // 16384 elems total
    int h = idx >> 12, rem = idx & 4095, o = rem >> 6, f = rem & 63;
    WT[idx] = __float2bfloat16(W[(h * F_ + f) * FH_ + o]);
}

// ---------------- K1: featsT = (X@W)^T via MFMA, fused ss/sn epilogue ----------------
// featsT[b][h][o][n]; ss/sn[b][h][n] = log2(e) * feats[b,h,n,:] . a_{self,neigh}[h]
__global__ __launch_bounds__(256) void k1_feats(const float* __restrict__ X,
                                                const __hip_bfloat16* __restrict__ WT,
                                                const float* __restrict__ a_self,
                                                const float* __restrict__ a_neigh,
                                                __hip_bfloat16* __restrict__ featsT,
                                                float* __restrict__ ss,
                                                float* __restrict__ sn) {
    __shared__ float a_lds[2][FH_];
    __shared__ __hip_bfloat16 c_lds[FH_ * 72];  // padded leading dim 72 vs 64
    const int nb = blockIdx.x, h = blockIdx.y, b = blockIdx.z;
    const int tid = threadIdx.x;
    if (tid < 64)       a_lds[0][tid] = a_self[h * FH_ + tid];
    else if (tid < 128) a_lds[1][tid - 64] = a_neigh[h * FH_ + tid - 64];
    __syncthreads();

    const int wave = tid >> 6, lane = tid & 63;
    const int m = lane & 15, q = lane >> 4;
    const int nl = wave * 16 + m;               // local column 0..63
    const int n = nb * 64 + nl;                 // B-frag column (node index)
    f32x4 acc[4] = {};
#pragma unroll
    for (int ks = 0; ks < 2; ++ks) {            // K = F = 64, two steps of 32
        const float* xp = X + ((size_t)(b * N_ + n)) * F_ + ks * 32 + q * 8;
        float4 x0 = *(const float4*)xp;
        float4 x1 = *(const float4*)(xp + 4);
        short8 bfrag;
        bfrag[0] = f2bf(x0.x); bfrag[1] = f2bf(x0.y);
        bfrag[2] = f2bf(x0.z); bfrag[3] = f2bf(x0.w);
        bfrag[4] = f2bf(x1.x); bfrag[5] = f2bf(x1.y);
        bfrag[6] = f2bf(x1.z); bfrag[7] = f2bf(x1.w);
#pragma unroll
        for (int ot = 0; ot < 4; ++ot) {        // 64 output features = 4 row tiles
            short8 afrag = *(const short8*)(WT + ((size_t)(h * FH_ + ot * 16 + m)) * F_ + ks * 32 + q * 8);
            acc[ot] = __builtin_amdgcn_mfma_f32_16x16x32_bf16(afrag, bfrag, acc[ot], 0, 0, 0);
        }
    }
    float ssv = 0.f, snv = 0.f;
#pragma unroll
    for (int ot = 0; ot < 4; ++ot) {
#pragma unroll
        for (int r = 0; r < 4; ++r) {
            int orow = ot * 16 + q * 4 + r;     // C: row=(lane>>4)*4+r, col=lane&15
            float v = acc[ot][r];
            c_lds[orow * 72 + nl] = __float2bfloat16(v);
            ssv += v * a_lds[0][orow];
            snv += v * a_lds[1][orow];
        }
    }
    // reduce over the 4 q-groups that share column n
    ssv += __shfl_xor(ssv, 16); ssv += __shfl_xor(ssv, 32);
    snv += __shfl_xor(snv, 16); snv += __shfl_xor(snv, 32);
    __syncthreads();
    {   // coalesced featsT store: thread t -> feature o = t>>2, 16-col chunk (t&3)
        int o = tid >> 2, c = (tid & 3) * 16;
        const __hip_bfloat16* src = c_lds + o * 72 + c;
        __hip_bfloat16* dst = featsT + ((size_t)(b * H_ + h) * FH_ + o) * N_ + nb * 64 + c;
        *(uint4*)dst       = *(const uint4*)src;        // 8 bf16
        *(uint4*)(dst + 8) = *(const uint4*)(src + 8);  // 8 bf16
    }
    if (lane < 16) {
        size_t idx = ((size_t)(b * H_ + h)) * N_ + n;
        ss[idx] = ssv * LOG2E;
        sn[idx] = snv * LOG2E;
    }
}

// ---------------- K3: fused mask+softmax(no-max)+PV MFMA + epilogue ----------------
// grid (N/16, B); block = 4 waves = 4 heads, same 16 rows (A stream shared via L1).
// LDS: sn only (32 KB) -> 4 blocks/CU. launch_bounds(256,4): 128-VGPR budget so the
// depth-1 prefetch of A+fv survives scheduling (R7 lesson: default bounds -> 64 VGPR
// budget -> compiler sinks prefetch -> serialized latency).
__global__ __launch_bounds__(256, 4) void k3_attn(const float* __restrict__ A,
                                                  const __hip_bfloat16* __restrict__ featsT,
                                                  const float* __restrict__ ss,
                                                  const float* __restrict__ sn,
                                                  const float* __restrict__ bias,
                                                  float* __restrict__ out) {
    __shared__ float sn_lds[H_ * N_];           // 32 KB
    const int tile = blockIdx.x, b = blockIdx.y;
    const int tid = threadIdx.x, h = tid >> 6, lane = tid & 63;
    const int m = lane & 15, q = lane >> 4;
    const int rowbase = tile * 16;

    {   // each wave stages its head's (log2e-scaled) sn row: 512 float4 slots
        const float4* src = (const float4*)(sn + ((size_t)(b * H_ + h)) * N_);
        float4* dst = (float4*)(sn_lds + h * N_);
#pragma unroll
        for (int i = 0; i < 8; ++i) dst[lane + i * 64] = src[lane + i * 64];
    }
    const float ssi = ss[((size_t)(b * H_ + h)) * N_ + rowbase + m];
    __syncthreads();

    const float* arow = A + ((size_t)(b * N_ + rowbase + m)) * N_ + q * 8;
    const __hip_bfloat16* fb = featsT + (((size_t)(b * H_ + h)) * FH_ + m) * N_ + q * 8;
    const float* snh = sn_lds + h * N_ + q * 8;

    f32x4 acc[4] = {};
    f32x4 accl = {};
    short8 ones;
#pragma unroll
    for (int s = 0; s < 8; ++s) ones[s] = (short)0x3F80;   // bf16 1.0

    // --- depth-1 software prefetch of the two global streams (A, fv) ---
    float4 cA0 = *(const float4*)(arow);
    float4 cA1 = *(const float4*)(arow + 4);
    short8 cF0 = *(const short8*)(fb);
    short8 cF1 = *(const short8*)(fb + (size_t)16 * N_);
    short8 cF2 = *(const short8*)(fb + (size_t)32 * N_);
    short8 cF3 = *(const short8*)(fb + (size_t)48 * N_);

#pragma unroll 2
    for (int jb = 0; jb < N_; jb += 32) {
        const int jn = (jb + 32) & (N_ - 1);    // wraps to 0 on last iter (stays in-bounds)
        float4 nA0 = *(const float4*)(arow + jn);
        float4 nA1 = *(const float4*)(arow + jn + 4);
        short8 nF0 = *(const short8*)(fb + jn);
        short8 nF1 = *(const short8*)(fb + (size_t)16 * N_ + jn);
        short8 nF2 = *(const short8*)(fb + (size_t)32 * N_ + jn);
        short8 nF3 = *(const short8*)(fb + (size_t)48 * N_ + jn);

        float4 sv0 = *(const float4*)(snh + jb);
        float4 sv1 = *(const float4*)(snh + jb + 4);
        float snv[8] = {sv0.x, sv0.y, sv0.z, sv0.w, sv1.x, sv1.y, sv1.z, sv1.w};
        float mk[8]  = {cA0.x, cA0.y, cA0.z, cA0.w, cA1.x, cA1.y, cA1.z, cA1.w};
        short8 p;
#pragma unroll
        for (int s = 0; s < 8; ++s) {
            float t = ssi + snv[s];
            float e = exp2f(fmaxf(t, 0.2f * t));    // exp2(leaky(s)), pre-scaled by log2e
            p[s] = f2bf(mk[s] * e);                 // adjacency mask in {0,1}
        }
        acc[0] = __builtin_amdgcn_mfma_f32_16x16x32_bf16(p, cF0, acc[0], 0, 0, 0);
        acc[1] = __builtin_amdgcn_mfma_f32_16x16x32_bf16(p, cF1, acc[1], 0, 0, 0);
        acc[2] = __builtin_amdgcn_mfma_f32_16x16x32_bf16(p, cF2, acc[2], 0, 0, 0);
        acc[3] = __builtin_amdgcn_mfma_f32_16x16x32_bf16(p, cF3, acc[3], 0, 0, 0);
        accl   = __builtin_amdgcn_mfma_f32_16x16x32_bf16(p, ones, accl, 0, 0, 0);

        cA0 = nA0; cA1 = nA1;
        cF0 = nF0; cF1 = nF1; cF2 = nF2; cF3 = nF3;
    }

    float bc[4];
#pragma unroll
    for (int ct = 0; ct < 4; ++ct) bc[ct] = bias[h * FH_ + ct * 16 + m];

#pragma unroll
    for (int r = 0; r < 4; ++r) {
        float inv = 1.0f / accl[r];             // row sum for row q*4+r (all cols identical)
        int gr = rowbase + q * 4 + r;
#pragma unroll
        for (int ct = 0; ct < 4; ++ct) {
            float v = acc[ct][r] * inv + bc[ct];
            out[((size_t)(b * N_) + gr) * C_ + h * FH_ + ct * 16 + m] = fmaxf(v, 0.0f);
        }
    }
}

extern "C" void kernel_launch(void* const* d_in, const int* in_sizes, int n_in,
                              void* d_out, int out_size, void* d_ws, size_t ws_size,
                              hipStream_t stream) {
    const float* X       = (const float*)d_in[0];
    const float* A       = (const float*)d_in[1];
    const float* W       = (const float*)d_in[2];
    const float* bias    = (const float*)d_in[3];
    const float* a_self  = (const float*)d_in[4];
    const float* a_neigh = (const float*)d_in[5];
    float* out = (float*)d_out;   // reference output dtype is float32

    char* ws = (char*)d_ws;
    __hip_bfloat16* featsT = (__hip_bfloat16*)(ws);             // 8 MB   [B][H][FH][N]
    __hip_bfloat16* WT     = (__hip_bfloat16*)(ws + 8388608);   // 32 KB  [H][FH][F]
    float* ss              = (float*)(ws + 8421376);            // 256 KB [B][H][N]
    float* sn              = (float*)(ws + 8683520);            // 256 KB [B][H][N]

    k0_wt    <<<64, 256, 0, stream>>>(W, WT);
    k1_feats <<<dim3(N_ / 64, H_, B_), 256, 0, stream>>>(X, WT, a_self, a_neigh, featsT, ss, sn);
    k3_attn  <<<dim3(N_ / 16, B_), 256, 0, stream>>>(A, featsT, ss, sn, bias, out);
}

// Round 9
// 340.652 us; speedup vs baseline: 1.1256x; 1.0389x over previous
//
#include <hip/hip_runtime.h>
#include <hip/hip_bf16.h>
#include <stdint.h>

#define B_ 8
#define N_ 2048
#define F_ 64
#define FH_ 64
#define H_ 4
#define C_ (H_*FH_)
#define LOG2E 1.44269504088896340736f

typedef short short8 __attribute__((ext_vector_type(8)));   // 8 bf16 raw bits (4 VGPRs)
typedef float f32x4 __attribute__((ext_vector_type(4)));

// float -> bf16 raw bits (RNE)
__device__ __forceinline__ short f2bf(float f) {
    __hip_bfloat16 h = __float2bfloat16(f);
    return __builtin_bit_cast(short, h);
}

// ---------------- K0: WT[h][o][f] = bf16(W[h][f][o]) ----------------
__global__ __launch_bounds__(256) void k0_wt(const float* __restrict__ W,
                                             __hip_bfloat16* __restrict__ WT) {
    int idx = blockIdx.x * 256 + threadIdx.x;   // 16384 elems total
    int h = idx >> 12, rem = idx & 4095, o = rem >> 6, f = rem & 63;
    WT[idx] = __float2bfloat16(W[(h * F_ + f) * FH_ + o]);
}

// ---------------- K1: featsT = (X@W)^T via MFMA, fused ss/sn epilogue ----------------
__global__ __launch_bounds__(256) void k1_feats(const float* __restrict__ X,
                                                const __hip_bfloat16* __restrict__ WT,
                                                const float* __restrict__ a_self,
                                                const float* __restrict__ a_neigh,
                                                __hip_bfloat16* __restrict__ featsT,
                                                float* __restrict__ ss,
                                                float* __restrict__ sn) {
    __shared__ float a_lds[2][FH_];
    __shared__ __hip_bfloat16 c_lds[FH_ * 72];  // padded leading dim 72 vs 64
    const int nb = blockIdx.x, h = blockIdx.y, b = blockIdx.z;
    const int tid = threadIdx.x;
    if (tid < 64)       a_lds[0][tid] = a_self[h * FH_ + tid];
    else if (tid < 128) a_lds[1][tid - 64] = a_neigh[h * FH_ + tid - 64];
    __syncthreads();

    const int wave = tid >> 6, lane = tid & 63;
    const int m = lane & 15, q = lane >> 4;
    const int nl = wave * 16 + m;               // local column 0..63
    const int n = nb * 64 + nl;                 // B-frag column (node index)
    f32x4 acc[4] = {};
#pragma unroll
    for (int ks = 0; ks < 2; ++ks) {            // K = F = 64, two steps of 32
        const float* xp = X + ((size_t)(b * N_ + n)) * F_ + ks * 32 + q * 8;
        float4 x0 = *(const float4*)xp;
        float4 x1 = *(const float4*)(xp + 4);
        short8 bfrag;
        bfrag[0] = f2bf(x0.x); bfrag[1] = f2bf(x0.y);
        bfrag[2] = f2bf(x0.z); bfrag[3] = f2bf(x0.w);
        bfrag[4] = f2bf(x1.x); bfrag[5] = f2bf(x1.y);
        bfrag[6] = f2bf(x1.z); bfrag[7] = f2bf(x1.w);
#pragma unroll
        for (int ot = 0; ot < 4; ++ot) {        // 64 output features = 4 row tiles
            short8 afrag = *(const short8*)(WT + ((size_t)(h * FH_ + ot * 16 + m)) * F_ + ks * 32 + q * 8);
            acc[ot] = __builtin_amdgcn_mfma_f32_16x16x32_bf16(afrag, bfrag, acc[ot], 0, 0, 0);
        }
    }
    float ssv = 0.f, snv = 0.f;
#pragma unroll
    for (int ot = 0; ot < 4; ++ot) {
#pragma unroll
        for (int r = 0; r < 4; ++r) {
            int orow = ot * 16 + q * 4 + r;     // C: row=(lane>>4)*4+r, col=lane&15
            float v = acc[ot][r];
            c_lds[orow * 72 + nl] = __float2bfloat16(v);
            ssv += v * a_lds[0][orow];
            snv += v * a_lds[1][orow];
        }
    }
    ssv += __shfl_xor(ssv, 16); ssv += __shfl_xor(ssv, 32);
    snv += __shfl_xor(snv, 16); snv += __shfl_xor(snv, 32);
    __syncthreads();
    {   // coalesced featsT store: thread t -> feature o = t>>2, 16-col chunk (t&3)
        int o = tid >> 2, c = (tid & 3) * 16;
        const __hip_bfloat16* src = c_lds + o * 72 + c;
        __hip_bfloat16* dst = featsT + ((size_t)(b * H_ + h) * FH_ + o) * N_ + nb * 64 + c;
        *(uint4*)dst       = *(const uint4*)src;        // 8 bf16
        *(uint4*)(dst + 8) = *(const uint4*)(src + 8);  // 8 bf16
    }
    if (lane < 16) {
        size_t idx = ((size_t)(b * H_ + h)) * N_ + n;
        ss[idx] = ssv * LOG2E;
        sn[idx] = snv * LOG2E;
    }
}

// ---------------- K3: fused mask+softmax(no-max)+PV MFMA + epilogue ----------------
// grid (N/64, H, B) = 1024 blocks; block = 1 head, 64 rows, 4 waves x 16 rows.
// LDS: e1/e2 tables for ONE head = 16 KB -> LDS permits 8 blocks/CU; grid caps 4.
// launch_bounds(256,3): 168-VGPR budget so the two-chain body never spills.
// Two independent accumulator chains (cols jb and jb+32) per iteration:
// 12 independent global loads + 10 MFMAs with no serial acc dependency.
// exp(leaky(si+sj)) = (hi>1 ? hi : lo), hi = e1i*e1j, lo = e2i*e2j (tables in LDS).
__global__ __launch_bounds__(256, 3) void k3_attn(const float* __restrict__ A,
                                                  const __hip_bfloat16* __restrict__ featsT,
                                                  const float* __restrict__ ss,
                                                  const float* __restrict__ sn,
                                                  const float* __restrict__ bias,
                                                  float* __restrict__ out) {
    __shared__ float e1_lds[N_];                // 8 KB: 2^sn_j
    __shared__ float e2_lds[N_];                // 8 KB: 2^(0.2 sn_j)
    const int tile = blockIdx.x, h = blockIdx.y, b = blockIdx.z;
    const int tid = threadIdx.x, wave = tid >> 6, lane = tid & 63;
    const int m = lane & 15, q = lane >> 4;
    const int rowbase = tile * 64 + wave * 16;

    {   // stage this head's exp tables: 512 float4 slots, 2 per thread
        const float4* snrow = (const float4*)(sn + ((size_t)(b * H_ + h)) * N_);
        float4* e1v = (float4*)e1_lds;
        float4* e2v = (float4*)e2_lds;
#pragma unroll
        for (int i = 0; i < 2; ++i) {
            int idx = tid + i * 256;
            float4 v = snrow[idx];
            float4 u1, u2;
            u1.x = exp2f(v.x); u1.y = exp2f(v.y); u1.z = exp2f(v.z); u1.w = exp2f(v.w);
            u2.x = exp2f(0.2f * v.x); u2.y = exp2f(0.2f * v.y);
            u2.z = exp2f(0.2f * v.z); u2.w = exp2f(0.2f * v.w);
            e1v[idx] = u1; e2v[idx] = u2;
        }
    }
    const float ssi = ss[((size_t)(b * H_ + h)) * N_ + rowbase + m];
    const float e1i = exp2f(ssi), e2i = exp2f(0.2f * ssi);
    __syncthreads();

    const float* arow = A + ((size_t)(b * N_ + rowbase + m)) * N_ + q * 8;
    const __hip_bfloat16* fb = featsT + (((size_t)(b * H_ + h)) * FH_ + m) * N_ + q * 8;
    const float* t1 = e1_lds + q * 8;
    const float* t2 = e2_lds + q * 8;

    f32x4 accA[4] = {}, accB[4] = {};           // two independent chains
    f32x4 acclA = {}, acclB = {};
    short8 ones;
#pragma unroll
    for (int s = 0; s < 8; ++s) ones[s] = (short)0x3F80;   // bf16 1.0

    for (int jb = 0; jb < N_; jb += 64) {
        // ---- issue all 12 global + 8 LDS loads up front (memory-level parallelism) ----
        float4 a00 = *(const float4*)(arow + jb);
        float4 a01 = *(const float4*)(arow + jb + 4);
        float4 a10 = *(const float4*)(arow + jb + 32);
        float4 a11 = *(const float4*)(arow + jb + 36);
        short8 f0 = *(const short8*)(fb + jb);
        short8 f1 = *(const short8*)(fb + (size_t)16 * N_ + jb);
        short8 f2 = *(const short8*)(fb + (size_t)32 * N_ + jb);
        short8 f3 = *(const short8*)(fb + (size_t)48 * N_ + jb);
        short8 g0 = *(const short8*)(fb + jb + 32);
        short8 g1 = *(const short8*)(fb + (size_t)16 * N_ + jb + 32);
        short8 g2 = *(const short8*)(fb + (size_t)32 * N_ + jb + 32);
        short8 g3 = *(const short8*)(fb + (size_t)48 * N_ + jb + 32);
        float4 e1a0 = *(const float4*)(t1 + jb);
        float4 e1a1 = *(const float4*)(t1 + jb + 4);
        float4 e1b0 = *(const float4*)(t1 + jb + 32);
        float4 e1b1 = *(const float4*)(t1 + jb + 36);
        float4 e2a0 = *(const float4*)(t2 + jb);
        float4 e2a1 = *(const float4*)(t2 + jb + 4);
        float4 e2b0 = *(const float4*)(t2 + jb + 32);
        float4 e2b1 = *(const float4*)(t2 + jb + 36);

        float e1a[8] = {e1a0.x, e1a0.y, e1a0.z, e1a0.w, e1a1.x, e1a1.y, e1a1.z, e1a1.w};
        float e2a[8] = {e2a0.x, e2a0.y, e2a0.z, e2a0.w, e2a1.x, e2a1.y, e2a1.z, e2a1.w};
        float mka[8] = {a00.x, a00.y, a00.z, a00.w, a01.x, a01.y, a01.z, a01.w};
        float e1b[8] = {e1b0.x, e1b0.y, e1b0.z, e1b0.w, e1b1.x, e1b1.y, e1b1.z, e1b1.w};
        float e2b[8] = {e2b0.x, e2b0.y, e2b0.z, e2b0.w, e2b1.x, e2b1.y, e2b1.z, e2b1.w};
        float mkb[8] = {a10.x, a10.y, a10.z, a10.w, a11.x, a11.y, a11.z, a11.w};

        short8 p0, p1;
#pragma unroll
        for (int s = 0; s < 8; ++s) {
            float hi0 = e1i * e1a[s], lo0 = e2i * e2a[s];
            float hi1 = e1i * e1b[s], lo1 = e2i * e2b[s];
            float v0 = (hi0 > 1.0f) ? hi0 : lo0;    // exp2(leaky(s)), sign test exact
            float v1 = (hi1 > 1.0f) ? hi1 : lo1;
            p0[s] = f2bf(mka[s] * v0);              // adjacency mask in {0,1}
            p1[s] = f2bf(mkb[s] * v1);
        }
        accA[0] = __builtin_amdgcn_mfma_f32_16x16x32_bf16(p0, f0, accA[0], 0, 0, 0);
        accB[0] = __builtin_amdgcn_mfma_f32_16x16x32_bf16(p1, g0, accB[0], 0, 0, 0);
        accA[1] = __builtin_amdgcn_mfma_f32_16x16x32_bf16(p0, f1, accA[1], 0, 0, 0);
        accB[1] = __builtin_amdgcn_mfma_f32_16x16x32_bf16(p1, g1, accB[1], 0, 0, 0);
        accA[2] = __builtin_amdgcn_mfma_f32_16x16x32_bf16(p0, f2, accA[2], 0, 0, 0);
        accB[2] = __builtin_amdgcn_mfma_f32_16x16x32_bf16(p1, g2, accB[2], 0, 0, 0);
        accA[3] = __builtin_amdgcn_mfma_f32_16x16x32_bf16(p0, f3, accA[3], 0, 0, 0);
        accB[3] = __builtin_amdgcn_mfma_f32_16x16x32_bf16(p1, g3, accB[3], 0, 0, 0);
        acclA   = __builtin_amdgcn_mfma_f32_16x16x32_bf16(p0, ones, acclA, 0, 0, 0);
        acclB   = __builtin_amdgcn_mfma_f32_16x16x32_bf16(p1, ones, acclB, 0, 0, 0);
    }

    float bc[4];
#pragma unroll
    for (int ct = 0; ct < 4; ++ct) bc[ct] = bias[h * FH_ + ct * 16 + m];

#pragma unroll
    for (int r = 0; r < 4; ++r) {
        float inv = 1.0f / (acclA[r] + acclB[r]);   // row sum (all cols identical)
        int gr = rowbase + q * 4 + r;
#pragma unroll
        for (int ct = 0; ct < 4; ++ct) {
            float v = (accA[ct][r] + accB[ct][r]) * inv + bc[ct];
            out[((size_t)(b * N_) + gr) * C_ + h * FH_ + ct * 16 + m] = fmaxf(v, 0.0f);
        }
    }
}

extern "C" void kernel_launch(void* const* d_in, const int* in_sizes, int n_in,
                              void* d_out, int out_size, void* d_ws, size_t ws_size,
                              hipStream_t stream) {
    const float* X       = (const float*)d_in[0];
    const float* A       = (const float*)d_in[1];
    const float* W       = (const float*)d_in[2];
    const float* bias    = (const float*)d_in[3];
    const float* a_self  = (const float*)d_in[4];
    const float* a_neigh = (const float*)d_in[5];
    float* out = (float*)d_out;   // reference output dtype is float32

    char* ws = (char*)d_ws;
    __hip_bfloat16* featsT = (__hip_bfloat16*)(ws);             // 8 MB   [B][H][FH][N]
    __hip_bfloat16* WT     = (__hip_bfloat16*)(ws + 8388608);   // 32 KB  [H][FH][F]
    float* ss              = (float*)(ws + 8421376);            // 256 KB [B][H][N]
    float* sn              = (float*)(ws + 8683520);            // 256 KB [B][H][N]

    k0_wt    <<<64, 256, 0, stream>>>(W, WT);
    k1_feats <<<dim3(N_ / 64, H_, B_), 256, 0, stream>>>(X, WT, a_self, a_neigh, featsT, ss, sn);
    k3_attn  <<<dim3(N_ / 64, H_, B_), 256, 0, stream>>>(A, featsT, ss, sn, bias, out);
}